// Round 7
// baseline (267.298 us; speedup 1.0000x reference)
//
#include <hip/hip_runtime.h>

typedef __fp16   f2  __attribute__((ext_vector_type(2)));
typedef _Float16 h4  __attribute__((ext_vector_type(4)));
typedef _Float16 v8h __attribute__((ext_vector_type(8)));
typedef float    v4f __attribute__((ext_vector_type(4)));
struct f2x2 { f2 lo, hi; };

#if __has_builtin(__builtin_amdgcn_exp2f)
#define FEXP2(x) __builtin_amdgcn_exp2f(x)   // raw v_exp_f32 (no ocml fixups)
#else
#define FEXP2(x) exp2f(x)
#endif

constexpr int Bn = 4, Nn = 2048, Dn = 1024, Hn = 16, DKn = 64, Mn = 8192;

// async global->LDS, 16B per lane; LDS dest = wave-uniform base + lane*16 (m104)
__device__ __forceinline__ void load_lds16(const _Float16* g, _Float16* l) {
    __builtin_amdgcn_global_load_lds(
        (const __attribute__((address_space(1))) void*)g,
        (__attribute__((address_space(3))) void*)l, 16, 0, 0);
}

// ---------------- elementwise fp32 -> f16 cast ----------------
__global__ __launch_bounds__(256) void cast_f16(const float* __restrict__ x,
                                                _Float16* __restrict__ y) {
    const int i = blockIdx.x * 256 + threadIdx.x;
    const float4 v = ((const float4*)x)[i];
    h4 o; o[0] = (_Float16)v.x; o[1] = (_Float16)v.y;
    o[2] = (_Float16)v.z; o[3] = (_Float16)v.w;
    ((h4*)y)[i] = o;
}

// ------- merged transpose+cast: 4 weights, W [k][n] fp32 -> Wt [n][k] f16 -------
__global__ __launch_bounds__(256) void castW4(const float* __restrict__ Wq,
                                              const float* __restrict__ Wk,
                                              const float* __restrict__ Wv,
                                              const float* __restrict__ Wo,
                                              _Float16* __restrict__ Wqkv,
                                              _Float16* __restrict__ Wto) {
    __shared__ float tile[32][33];
    const int which = blockIdx.x >> 10, bid = blockIdx.x & 1023;
    const float* W = which == 0 ? Wq : which == 1 ? Wk : which == 2 ? Wv : Wo;
    _Float16* Dst = which < 3 ? (Wqkv + ((size_t)which << 20)) : Wto;
    const int bx = bid & 31, by = bid >> 5;
    const int t = threadIdx.x;
    const int r = t >> 3, c4 = (t & 7) * 4;
    const float4 v = *(const float4*)&W[(size_t)(by * 32 + r) * Dn + bx * 32 + c4];
    tile[r][c4 + 0] = v.x; tile[r][c4 + 1] = v.y;
    tile[r][c4 + 2] = v.z; tile[r][c4 + 3] = v.w;
    __syncthreads();
    h4 o;
    o[0] = (_Float16)tile[c4 + 0][r];
    o[1] = (_Float16)tile[c4 + 1][r];
    o[2] = (_Float16)tile[c4 + 2][r];
    o[3] = (_Float16)tile[c4 + 3][r];
    *(h4*)&Dst[(size_t)(bx * 32 + r) * Dn + by * 32 + c4] = o;
}

// ======================================================================
// GEMMs: R6 structure (m201-style phases). After 6 schedule variants all
// measured 2830+-80 cyc/K-step, the schedule is exonerated as the lever at
// this shape; keep the verified-correct best and leave it alone.
// Bank-conflict-free swizzle (R2, measured 0 conflicts) documented in the
// git history; stage-3-ahead slot schedule with counted vmcnt (R3 ledger).
// ======================================================================
#define MFMA16(A, B, C) __builtin_amdgcn_mfma_f32_16x16x32_f16((A), (B), (C), 0, 0, 0)

// ---------- fused QKV GEMM: [8192,1024] @ [3072,1024]^T ----------
// 256x256 tile, per-wave 128x64 (2M x 4N). grid 32*12 = 384 blocks.
__global__ __launch_bounds__(512, 2) void gemmqkv(const _Float16* __restrict__ A,
                                                  const _Float16* __restrict__ Wt,
                                                  _Float16* __restrict__ Qo,
                                                  _Float16* __restrict__ Ko,
                                                  _Float16* __restrict__ Vo)
{
    __shared__ __align__(16) _Float16 As[4 * 8192];
    __shared__ __align__(16) _Float16 Bs[4 * 8192];
    const int bx = blockIdx.x % 12, by = blockIdx.x / 12;
    const int m0 = by * 256, n0 = bx * 256;
    const _Float16* Abase = A + (size_t)m0 * Dn;
    const _Float16* Bbase = Wt + (size_t)n0 * Dn;

    const int t = threadIdx.x, lane = t & 63, w = t >> 6;
    const int quad = lane >> 4, l16 = lane & 15;
    const int wm = w >> 2, wn = w & 3;
    const int rA = t >> 2;
    const int gc = ((t & 3) ^ ((t >> 3) & 3)) * 8;   // source-side XOR swizzle
    const _Float16* pA0 = Abase + (size_t)rA * Dn + gc;
    const _Float16* pA1 = pA0 + (size_t)128 * Dn;    // A rows 128..255
    const _Float16* pB0 = Bbase + (size_t)rA * Dn + gc;
    const _Float16* pB1 = pB0 + (size_t)128 * Dn;    // B rows 128..255
    auto stageA = [&](int ts, int sh) {
        const int reg = (ts & 1) * 2 + sh, ko = ts * 64 + sh * 32;
        load_lds16(pA0 + ko, As + reg * 8192 + w * 512);
        load_lds16(pA1 + ko, As + reg * 8192 + 4096 + w * 512);
    };
    auto stageB = [&](int ts, int sh) {
        const int reg = (ts & 1) * 2 + sh, ko = ts * 64 + sh * 32;
        load_lds16(pB0 + ko, Bs + reg * 8192 + w * 512);
        load_lds16(pB1 + ko, Bs + reg * 8192 + 4096 + w * 512);
    };
    const int swz  = (quad ^ ((l16 >> 1) & 3)) * 8;
    const int aoff = (wm * 128 + l16) * 32 + swz;
    const int boff = (wn * 64 + l16) * 32 + swz;

    v4f acc[8][4];
#pragma unroll
    for (int i = 0; i < 8; ++i)
#pragma unroll
        for (int j = 0; j < 4; ++j) acc[i][j] = v4f{0.f, 0.f, 0.f, 0.f};

    // prologue: slots 0,1,2 (A,B pairs in order); vmcnt(8) -> slot 0 done
    stageA(0, 0); stageB(0, 0); stageA(0, 1); stageB(0, 1); stageA(1, 0); stageB(1, 0);
    asm volatile("s_waitcnt vmcnt(8)" ::: "memory");
    __builtin_amdgcn_s_barrier();

#define QKV_KSTEP(REG, TS, SH, DOST, VM, DOVM) do {                              \
    const _Float16* Ab_ = As + (REG) * 8192 + aoff;                              \
    const _Float16* Bb_ = Bs + (REG) * 8192 + boff;                              \
    v8h aL[4], aH[4], bL[4];                                                     \
    _Pragma("unroll") for (int q2 = 0; q2 < 4; ++q2) {                           \
        aL[q2] = *(const v8h*)(Ab_ + q2 * 512);                                  \
        bL[q2] = *(const v8h*)(Bb_ + q2 * 512);                                  \
    }                                                                            \
    if (DOST) stageA((TS), (SH));                                                \
    __builtin_amdgcn_s_barrier();                                                \
    asm volatile("s_waitcnt lgkmcnt(0)" ::: "memory");                           \
    __builtin_amdgcn_s_setprio(1);                                               \
    _Pragma("unroll") for (int i2 = 0; i2 < 4; ++i2)                             \
        _Pragma("unroll") for (int j2 = 0; j2 < 4; ++j2)                         \
            acc[i2][j2] = MFMA16(aL[i2], bL[j2], acc[i2][j2]);                   \
    __builtin_amdgcn_s_setprio(0);                                               \
    __builtin_amdgcn_s_barrier();                                                \
    _Pragma("unroll") for (int q2 = 0; q2 < 4; ++q2)                             \
        aH[q2] = *(const v8h*)(Ab_ + 2048 + q2 * 512);                           \
    if (DOST) stageB((TS), (SH));                                                \
    __builtin_amdgcn_s_barrier();                                                \
    asm volatile("s_waitcnt lgkmcnt(0)" ::: "memory");                           \
    __builtin_amdgcn_s_setprio(1);                                               \
    _Pragma("unroll") for (int i2 = 0; i2 < 4; ++i2)                             \
        _Pragma("unroll") for (int j2 = 0; j2 < 4; ++j2)                         \
            acc[4 + i2][j2] = MFMA16(aH[i2], bL[j2], acc[4 + i2][j2]);           \
    __builtin_amdgcn_s_setprio(0);                                               \
    if (DOVM) asm volatile("s_waitcnt " VM ::: "memory");                        \
    __builtin_amdgcn_s_barrier();                                                \
} while (0)

    // 32 K-steps; main loop p=0..27, peel 28..31 with tapered waits
    for (int tt = 0; tt < 14; tt += 2) {
        QKV_KSTEP(0, tt + 1, 1, true, "vmcnt(8)", true);
        QKV_KSTEP(1, tt + 2, 0, true, "vmcnt(8)", true);
        QKV_KSTEP(2, tt + 2, 1, true, "vmcnt(8)", true);
        QKV_KSTEP(3, tt + 3, 0, true, "vmcnt(8)", true);
    }
    QKV_KSTEP(0, 15, 1, true,  "vmcnt(8)", true);   // p=28: stages last slot 31
    QKV_KSTEP(1, 0, 0, false, "vmcnt(4)", true);    // p=29
    QKV_KSTEP(2, 0, 0, false, "vmcnt(0)", true);    // p=30
    QKV_KSTEP(3, 0, 0, false, "vmcnt(0)", false);   // p=31 (no wait)
#undef QKV_KSTEP

    const int sec = n0 >> 10;                      // block-uniform: 0=Q 1=K 2=V
    if (sec < 2) {
        _Float16* C = sec ? Ko : Qo;
        // Q pre-scaled by 1/sqrt(DK) * log2(e) so flash uses exp2 directly
        const float scale = sec ? 1.0f : 0.125f * 1.44269504f;
#pragma unroll
        for (int mf = 0; mf < 8; ++mf) {
            const int mbase = m0 + wm * 128 + mf * 16 + quad * 4;
#pragma unroll
            for (int nf = 0; nf < 4; ++nf) {
                const int nl = (n0 + wn * 64 + nf * 16 + l16) & 1023;
                const int h = nl >> 6, dk = nl & 63;
#pragma unroll
                for (int r = 0; r < 4; ++r) {
                    const int m = mbase + r, b = m >> 11, nr = m & (Nn - 1);
                    C[((size_t)(b * Hn + h) * Nn + nr) * DKn + dk] = (_Float16)(acc[mf][nf][r] * scale);
                }
            }
        }
    } else {
#pragma unroll
        for (int mf = 0; mf < 8; ++mf) {
            const int mbase = m0 + wm * 128 + mf * 16 + quad * 4;
            const int b = mbase >> 11, nr = mbase & (Nn - 1);
#pragma unroll
            for (int nf = 0; nf < 4; ++nf) {
                const int nl = (n0 + wn * 64 + nf * 16 + l16) & 1023;
                const int h = nl >> 6, dk = nl & 63;
                h4 o; o[0] = (_Float16)acc[mf][nf][0]; o[1] = (_Float16)acc[mf][nf][1];
                o[2] = (_Float16)acc[mf][nf][2]; o[3] = (_Float16)acc[mf][nf][3];
                *(h4*)&Vo[((size_t)(b * Hn + h) * DKn + dk) * Nn + nr] = o;
            }
        }
    }
}

// ---------- output GEMM: [8192,1024] @ [1024,1024]^T -> fp32 row-major ----------
// 256x128 tile (grid 256 = exactly 1 full round of 256 CUs), per-wave 64x64.
__global__ __launch_bounds__(512, 2) void gemmo(const _Float16* __restrict__ A,
                                                const _Float16* __restrict__ Wt,
                                                float* __restrict__ C)
{
    __shared__ __align__(16) _Float16 As[4 * 8192];
    __shared__ __align__(16) _Float16 Bs[4 * 4096];
    const int bx = blockIdx.x & 7, by = blockIdx.x >> 3;
    const int m0 = by * 256, n0 = bx * 128;
    const _Float16* Abase = A + (size_t)m0 * Dn;
    const _Float16* Bbase = Wt + (size_t)n0 * Dn;

    const int t = threadIdx.x, lane = t & 63, w = t >> 6;
    const int quad = lane >> 4, l16 = lane & 15;
    const int wm = w & 3, wn = w >> 2;
    const int rA = t >> 2;
    const int gc = ((t & 3) ^ ((t >> 3) & 3)) * 8;
    const _Float16* pA0 = Abase + (size_t)rA * Dn + gc;
    const _Float16* pA1 = pA0 + (size_t)128 * Dn;
    const _Float16* pB0 = Bbase + (size_t)rA * Dn + gc;
    auto stage3 = [&](int ts, int sh) {
        const int reg = (ts & 1) * 2 + sh, ko = ts * 64 + sh * 32;
        load_lds16(pA0 + ko, As + reg * 8192 + w * 512);
        load_lds16(pA1 + ko, As + reg * 8192 + 4096 + w * 512);
        load_lds16(pB0 + ko, Bs + reg * 4096 + w * 512);
    };
    const int swz  = (quad ^ ((l16 >> 1) & 3)) * 8;
    const int aoff = (wm * 64 + l16) * 32 + swz;
    const int boff = (wn * 64 + l16) * 32 + swz;

    v4f acc[4][4];
#pragma unroll
    for (int i = 0; i < 4; ++i)
#pragma unroll
        for (int j = 0; j < 4; ++j) acc[i][j] = v4f{0.f, 0.f, 0.f, 0.f};

    stage3(0, 0); stage3(0, 1); stage3(1, 0);    // prologue: slots 0,1,2
    asm volatile("s_waitcnt vmcnt(6)" ::: "memory");
    __builtin_amdgcn_s_barrier();

#define O_KSTEP(REG, TS, SH, DOST, VM, DOVM) do {                                \
    const _Float16* Ab_ = As + (REG) * 8192 + aoff;                              \
    const _Float16* Bb_ = Bs + (REG) * 4096 + boff;                              \
    v8h aL[4], bL[4];                                                            \
    _Pragma("unroll") for (int q2 = 0; q2 < 4; ++q2) {                           \
        aL[q2] = *(const v8h*)(Ab_ + q2 * 512);                                  \
        bL[q2] = *(const v8h*)(Bb_ + q2 * 512);                                  \
    }                                                                            \
    if (DOST) stage3((TS), (SH));                                                \
    __builtin_amdgcn_s_barrier();                                                \
    asm volatile("s_waitcnt lgkmcnt(0)" ::: "memory");                           \
    __builtin_amdgcn_s_setprio(1);                                               \
    _Pragma("unroll") for (int i2 = 0; i2 < 4; ++i2)                             \
        _Pragma("unroll") for (int j2 = 0; j2 < 4; ++j2)                         \
            acc[i2][j2] = MFMA16(aL[i2], bL[j2], acc[i2][j2]);                   \
    __builtin_amdgcn_s_setprio(0);                                               \
    if (DOVM) asm volatile("s_waitcnt " VM ::: "memory");                        \
    __builtin_amdgcn_s_barrier();                                                \
} while (0)

    for (int tt = 0; tt < 14; tt += 2) {
        O_KSTEP(0, tt + 1, 1, true, "vmcnt(6)", true);
        O_KSTEP(1, tt + 2, 0, true, "vmcnt(6)", true);
        O_KSTEP(2, tt + 2, 1, true, "vmcnt(6)", true);
        O_KSTEP(3, tt + 3, 0, true, "vmcnt(6)", true);
    }
    O_KSTEP(0, 15, 1, true,  "vmcnt(6)", true);   // p=28
    O_KSTEP(1, 0, 0, false, "vmcnt(3)", true);    // p=29
    O_KSTEP(2, 0, 0, false, "vmcnt(0)", true);    // p=30
    O_KSTEP(3, 0, 0, false, "vmcnt(0)", false);   // p=31
#undef O_KSTEP

#pragma unroll
    for (int mf = 0; mf < 4; ++mf) {
        const int mbase = m0 + wm * 64 + mf * 16 + quad * 4;
#pragma unroll
        for (int nf = 0; nf < 4; ++nf) {
            const int n = n0 + wn * 64 + nf * 16 + l16;
#pragma unroll
            for (int r = 0; r < 4; ++r)
                C[(size_t)(mbase + r) * Dn + n] = acc[mf][nf][r];
        }
    }
}

// ---------------- flash v6: double-buffered K/V staging ----------------
// R7 change: the old loop did stage(kt) -> __syncthreads() (FULL vmcnt(0)
// drain) -> compute -> __syncthreads(): zero prefetch, full HBM latency
// (~900 cyc) + DMA drain exposed per 64-key tile. Now KS/VS are [2] and
// iteration kt does: stage(kt+1, buf^1) -> s_waitcnt vmcnt(4) (waits only
// tile kt's 4 loads; next tile stays in flight = T4 counted-vmcnt) ->
// s_barrier -> compute(kt on buf) -> s_barrier.
// Hazards: RAW on buf = per-wave vmcnt(4) + barrier (all waves' DMA for kt
// done & published). WAR: stage(kt+2) overwrites buf read by compute(kt);
// a wave reaches the end barrier only after its ds_reads were consumed
// (lgkm waits precede the MFMAs it issued), and stage(kt+2) issues after
// that barrier. Last iteration: vmcnt(0). Compute code unchanged.
// LDS: 2*8KB K + 2*8KB V + 16KB Ps = 48KB -> 3 blocks/CU.
// ======================================================================
__global__ __launch_bounds__(256) void flashv5(const _Float16* __restrict__ Q,
                                               const _Float16* __restrict__ K,
                                               const _Float16* __restrict__ Vt,
                                               _Float16* __restrict__ O)
{
    __shared__ __align__(16) _Float16 KS[2][64 * 64];  // [key][dk], chunk-swizzled
    __shared__ __align__(16) _Float16 VS[2][64 * 64];  // [dk][key], chunk-swizzled
    __shared__ __align__(16) _Float16 Ps[4][32 * 64];  // per-wave P, chunk-swizzled

    const int t = threadIdx.x;
    const int lane = t & 63, w = t >> 6;
    const int quad = lane >> 4, l16 = lane & 15;
    const int bh = blockIdx.x & 63;                    // fast-varying (L2 locality)
    const int qtile = 15 - (blockIdx.x >> 6);          // heaviest first
    const int b = bh >> 4, h = bh & 15;
    const int qb = qtile * 128 + w * 32;

    const _Float16* Qg = Q  + (size_t)bh * Nn * DKn;
    const _Float16* Kg = K  + (size_t)bh * Nn * DKn;
    const _Float16* Vg = Vt + (size_t)bh * DKn * Nn;

    auto stage = [&](int kt, int buf) {                // 4 loads per lane
        const int k0 = kt * 64;
#pragma unroll
        for (int jj = 0; jj < 2; ++jj) {
            const int ci = jj * 256 + w * 64 + lane;   // slot (r*8 + c)
            const int r = ci >> 3, c = ci & 7;
            const int gc = (c ^ (r & 7)) * 8;          // XOR chunk swizzle
            load_lds16(Kg + (size_t)(k0 + r) * DKn + gc, &KS[buf][(jj * 256 + w * 64) * 8]);
            load_lds16(Vg + (size_t)r * Nn + k0 + gc,    &VS[buf][(jj * 256 + w * 64) * 8]);
        }
    };
#define SWZ(arr, r, c) (*(const v8h*)&(arr)[(r) * 64 + (((c) ^ ((r) & 7)) * 8)])

    v8h qf[2][2];
#pragma unroll
    for (int qq = 0; qq < 2; ++qq)
#pragma unroll
        for (int ks = 0; ks < 2; ++ks)
            qf[qq][ks] = *(const v8h*)&Qg[(size_t)(qb + qq * 16 + l16) * DKn + ks * 32 + quad * 8];

    v8h ones;
#pragma unroll
    for (int i = 0; i < 8; ++i) ones[i] = (_Float16)1.0f;

    v4f o[2][4];
#pragma unroll
    for (int mq = 0; mq < 2; ++mq)
#pragma unroll
        for (int nt = 0; nt < 4; ++nt) o[mq][nt] = v4f{0.f, 0.f, 0.f, 0.f};
    v4f ol[2] = {v4f{0.f, 0.f, 0.f, 0.f}, v4f{0.f, 0.f, 0.f, 0.f}};

    const int NKT  = 2 * qtile + 2;                    // block-uniform
    const int diag = 2 * qtile + (w >> 1);             // wave's masked tile

    stage(0, 0);                                       // prologue
    for (int kt = 0; kt < NKT; ++kt) {
        const int cur = kt & 1;
        if (kt + 1 < NKT) {
            stage(kt + 1, cur ^ 1);                    // prefetch next tile
            asm volatile("s_waitcnt vmcnt(4)" ::: "memory");   // tile kt done
        } else {
            asm volatile("s_waitcnt vmcnt(0)" ::: "memory");
        }
        __builtin_amdgcn_s_barrier();                  // publish tile kt
        if (kt <= diag) {
            const int k0 = kt * 64;
            const _Float16* KSc = KS[cur];
            const _Float16* VSc = VS[cur];
            auto ptile = [&](bool domask) {
#pragma unroll
                for (int kk = 0; kk < 4; ++kk) {
                    v4f s0 = v4f{0.f, 0.f, 0.f, 0.f}, s1 = v4f{0.f, 0.f, 0.f, 0.f};
#pragma unroll
                    for (int ks = 0; ks < 2; ++ks) {
                        const v8h ak = SWZ(KSc, kk * 16 + l16, ks * 4 + quad);
                        s0 = __builtin_amdgcn_mfma_f32_16x16x32_f16(ak, qf[0][ks], s0, 0, 0, 0);
                        s1 = __builtin_amdgcn_mfma_f32_16x16x32_f16(ak, qf[1][ks], s1, 0, 0, 0);
                    }
                    const int key0 = k0 + kk * 16 + quad * 4;
#pragma unroll
                    for (int qq = 0; qq < 2; ++qq) {
                        const v4f sv = qq ? s1 : s0;
                        const int q = qb + qq * 16 + l16;
                        float p[4];
#pragma unroll
                        for (int r = 0; r < 4; ++r) {
                            float x = sv[r];
                            if (domask) x = (key0 + r > q) ? -1e9f : x;
                            p[r] = FEXP2(x);           // Q pre-scaled by log2e/8
                        }
                        f2x2 pkr;
                        pkr.lo = __builtin_amdgcn_cvt_pkrtz(p[0], p[1]);
                        pkr.hi = __builtin_amdgcn_cvt_pkrtz(p[2], p[3]);
                        const h4 pk = __builtin_bit_cast(h4, pkr);
                        const int prow = qq * 16 + l16;
                        const int pch  = kk * 2 + (quad >> 1);
                        *(h4*)&Ps[w][prow * 64 + ((pch ^ (prow & 7)) * 8 + (quad & 1) * 4)] = pk;
                    }
                }
#pragma unroll
                for (int ks = 0; ks < 2; ++ks)
#pragma unroll
                    for (int mq = 0; mq < 2; ++mq) {
                        const int arow = mq * 16 + l16;
                        const int ach  = ks * 4 + quad;
                        const v8h a = *(const v8h*)&Ps[w][arow * 64 + ((ach ^ (arow & 7)) * 8)];
#pragma unroll
                        for (int nt = 0; nt < 4; ++nt) {
                            const v8h bvv = SWZ(VSc, nt * 16 + l16, ks * 4 + quad);
                            o[mq][nt] = __builtin_amdgcn_mfma_f32_16x16x32_f16(a, bvv, o[mq][nt], 0, 0, 0);
                        }
                        ol[mq] = __builtin_amdgcn_mfma_f32_16x16x32_f16(a, ones, ol[mq], 0, 0, 0);
                    }
            };
            if (kt == diag) ptile(true); else ptile(false);
        }
        asm volatile("" ::: "memory");                 // pin LDS reads inside iter
        __builtin_amdgcn_s_barrier();                  // all reads done before next stage
    }
#undef SWZ

    _Float16* Op = O + (size_t)b * Nn * Dn + h * DKn;
#pragma unroll
    for (int mq = 0; mq < 2; ++mq)
#pragma unroll
        for (int r = 0; r < 4; ++r) {
            const float li = 1.0f / ol[mq][r];
            const int qrow = qb + mq * 16 + quad * 4 + r;
#pragma unroll
            for (int nt = 0; nt < 4; ++nt)
                Op[(size_t)qrow * Dn + nt * 16 + l16] = (_Float16)(o[mq][nt][r] * li);
        }
}

extern "C" void kernel_launch(void* const* d_in, const int* in_sizes, int n_in,
                              void* d_out, int out_size, void* d_ws, size_t ws_size,
                              hipStream_t stream)
{
    const float* X  = (const float*)d_in[0];
    // d_in[1] = additive causal mask; regenerated inline in flashv5.
    const float* Wq = (const float*)d_in[2];
    const float* Wk = (const float*)d_in[3];
    const float* Wv = (const float*)d_in[4];
    const float* Wo = (const float*)d_in[5];

    char* ws = (char*)d_ws;
    _Float16* Xh   = (_Float16*)ws;                      // 16 MB
    _Float16* Wqkv = (_Float16*)(ws + (16u << 20));      // 6 MB  [3072][1024]
    _Float16* Wto  = Wqkv + (3u << 20);                  // 2 MB
    _Float16* Qh   = Wto + (1u << 20);                   // 16 MB each
    _Float16* Kh   = Qh + (size_t)Mn * Dn;
    _Float16* Vth  = Kh + (size_t)Mn * Dn;
    _Float16* Ah   = Vth + (size_t)Mn * Dn;              // total 88 MB

    cast_f16<<<(Mn * Dn / 4) / 256, 256, 0, stream>>>(X, Xh);
    castW4<<<4096, 256, 0, stream>>>(Wq, Wk, Wv, Wo, Wqkv, Wto);
    gemmqkv<<<384, 512, 0, stream>>>(Xh, Wqkv, Qh, Kh, Vth);
    flashv5<<<1024, 256, 0, stream>>>(Qh, Kh, Vth, Ah);
    gemmo<<<256, 512, 0, stream>>>(Ah, Wto, (float*)d_out);
}

// Round 9
// 252.831 us; speedup vs baseline: 1.0572x; 1.0572x over previous
//
#include <hip/hip_runtime.h>

typedef __fp16   f2  __attribute__((ext_vector_type(2)));
typedef _Float16 h4  __attribute__((ext_vector_type(4)));
typedef _Float16 v8h __attribute__((ext_vector_type(8)));
typedef float    v4f __attribute__((ext_vector_type(4)));
struct f2x2 { f2 lo, hi; };

#if __has_builtin(__builtin_amdgcn_exp2f)
#define FEXP2(x) __builtin_amdgcn_exp2f(x)   // raw v_exp_f32 (no ocml fixups)
#else
#define FEXP2(x) exp2f(x)
#endif

constexpr int Bn = 4, Nn = 2048, Dn = 1024, Hn = 16, DKn = 64, Mn = 8192;

// async global->LDS, 16B per lane; LDS dest = wave-uniform base + lane*16 (m104)
__device__ __forceinline__ void load_lds16(const _Float16* g, _Float16* l) {
    __builtin_amdgcn_global_load_lds(
        (const __attribute__((address_space(1))) void*)g,
        (__attribute__((address_space(3))) void*)l, 16, 0, 0);
}

// ---- merged cast kernel: blocks [0,8192) = X fp32->f16; [8192,12288) = W transpose+cast ----
__global__ __launch_bounds__(256) void castAll(const float* __restrict__ x,
                                               _Float16* __restrict__ y,
                                               const float* __restrict__ Wq,
                                               const float* __restrict__ Wk,
                                               const float* __restrict__ Wv,
                                               const float* __restrict__ Wo,
                                               _Float16* __restrict__ Wqkv,
                                               _Float16* __restrict__ Wto) {
    __shared__ float tile[32][33];
    const int t = threadIdx.x;
    if (blockIdx.x < 8192) {
        const int i = blockIdx.x * 256 + t;
        const float4 v = ((const float4*)x)[i];
        h4 o; o[0] = (_Float16)v.x; o[1] = (_Float16)v.y;
        o[2] = (_Float16)v.z; o[3] = (_Float16)v.w;
        ((h4*)y)[i] = o;
        return;
    }
    const int wb = blockIdx.x - 8192;
    const int which = wb >> 10, bid = wb & 1023;
    const float* W = which == 0 ? Wq : which == 1 ? Wk : which == 2 ? Wv : Wo;
    _Float16* Dst = which < 3 ? (Wqkv + ((size_t)which << 20)) : Wto;
    const int bx = bid & 31, by = bid >> 5;
    const int r = t >> 3, c4 = (t & 7) * 4;
    const float4 v = *(const float4*)&W[(size_t)(by * 32 + r) * Dn + bx * 32 + c4];
    tile[r][c4 + 0] = v.x; tile[r][c4 + 1] = v.y;
    tile[r][c4 + 2] = v.z; tile[r][c4 + 3] = v.w;
    __syncthreads();
    h4 o;
    o[0] = (_Float16)tile[c4 + 0][r];
    o[1] = (_Float16)tile[c4 + 1][r];
    o[2] = (_Float16)tile[c4 + 2][r];
    o[3] = (_Float16)tile[c4 + 3][r];
    *(h4*)&Dst[(size_t)(bx * 32 + r) * Dn + by * 32 + c4] = o;
}

// ======================================================================
// GEMMs: R6 structure (m201-style phases; 6 schedule variants all measured
// 2830+-80 cyc/K-step -> schedule exonerated, kept as verified-correct best).
// R8 change: bijective XCD-aware block swizzle (T1, m192/m204). Without it,
// blocks sharing an A-panel round-robin across the 8 XCD L2s -> every L2
// pulls every panel -> FETCH_SIZE 78.9MB vs 22MB unique (3.6x over-fetch).
// wgid = (bid & 7) * (nwg/8) + (bid >> 3): each XCD gets a contiguous tile
// range = 4 A-panels (2MB, L2-resident), bx sweeping inside the XCD.
// Bank-conflict-free swizzle (R2, measured 0 conflicts); stage-3-ahead slot
// schedule with counted vmcnt (R3 hazard ledger).
// ======================================================================
#define MFMA16(A, B, C) __builtin_amdgcn_mfma_f32_16x16x32_f16((A), (B), (C), 0, 0, 0)

// ---------- fused QKV GEMM: [8192,1024] @ [3072,1024]^T ----------
// 256x256 tile, per-wave 128x64 (2M x 4N). grid 32*12 = 384 blocks.
__global__ __launch_bounds__(512, 2) void gemmqkv(const _Float16* __restrict__ A,
                                                  const _Float16* __restrict__ Wt,
                                                  _Float16* __restrict__ Qo,
                                                  _Float16* __restrict__ Ko,
                                                  _Float16* __restrict__ Vo)
{
    __shared__ __align__(16) _Float16 As[4 * 8192];
    __shared__ __align__(16) _Float16 Bs[4 * 8192];
    // XCD swizzle: 384 % 8 == 0 -> simple bijective chunked map (48 tiles/XCD)
    const int wgid = (blockIdx.x & 7) * 48 + (blockIdx.x >> 3);
    const int bx = wgid % 12, by = wgid / 12;
    const int m0 = by * 256, n0 = bx * 256;
    const _Float16* Abase = A + (size_t)m0 * Dn;
    const _Float16* Bbase = Wt + (size_t)n0 * Dn;

    const int t = threadIdx.x, lane = t & 63, w = t >> 6;
    const int quad = lane >> 4, l16 = lane & 15;
    const int wm = w >> 2, wn = w & 3;
    const int rA = t >> 2;
    const int gc = ((t & 3) ^ ((t >> 3) & 3)) * 8;   // source-side XOR swizzle
    const _Float16* pA0 = Abase + (size_t)rA * Dn + gc;
    const _Float16* pA1 = pA0 + (size_t)128 * Dn;    // A rows 128..255
    const _Float16* pB0 = Bbase + (size_t)rA * Dn + gc;
    const _Float16* pB1 = pB0 + (size_t)128 * Dn;    // B rows 128..255
    auto stageA = [&](int ts, int sh) {
        const int reg = (ts & 1) * 2 + sh, ko = ts * 64 + sh * 32;
        load_lds16(pA0 + ko, As + reg * 8192 + w * 512);
        load_lds16(pA1 + ko, As + reg * 8192 + 4096 + w * 512);
    };
    auto stageB = [&](int ts, int sh) {
        const int reg = (ts & 1) * 2 + sh, ko = ts * 64 + sh * 32;
        load_lds16(pB0 + ko, Bs + reg * 8192 + w * 512);
        load_lds16(pB1 + ko, Bs + reg * 8192 + 4096 + w * 512);
    };
    const int swz  = (quad ^ ((l16 >> 1) & 3)) * 8;
    const int aoff = (wm * 128 + l16) * 32 + swz;
    const int boff = (wn * 64 + l16) * 32 + swz;

    v4f acc[8][4];
#pragma unroll
    for (int i = 0; i < 8; ++i)
#pragma unroll
        for (int j = 0; j < 4; ++j) acc[i][j] = v4f{0.f, 0.f, 0.f, 0.f};

    // prologue: slots 0,1,2 (A,B pairs in order); vmcnt(8) -> slot 0 done
    stageA(0, 0); stageB(0, 0); stageA(0, 1); stageB(0, 1); stageA(1, 0); stageB(1, 0);
    asm volatile("s_waitcnt vmcnt(8)" ::: "memory");
    __builtin_amdgcn_s_barrier();

#define QKV_KSTEP(REG, TS, SH, DOST, VM, DOVM) do {                              \
    const _Float16* Ab_ = As + (REG) * 8192 + aoff;                              \
    const _Float16* Bb_ = Bs + (REG) * 8192 + boff;                              \
    v8h aL[4], aH[4], bL[4];                                                     \
    _Pragma("unroll") for (int q2 = 0; q2 < 4; ++q2) {                           \
        aL[q2] = *(const v8h*)(Ab_ + q2 * 512);                                  \
        bL[q2] = *(const v8h*)(Bb_ + q2 * 512);                                  \
    }                                                                            \
    if (DOST) stageA((TS), (SH));                                                \
    __builtin_amdgcn_s_barrier();                                                \
    asm volatile("s_waitcnt lgkmcnt(0)" ::: "memory");                           \
    __builtin_amdgcn_s_setprio(1);                                               \
    _Pragma("unroll") for (int i2 = 0; i2 < 4; ++i2)                             \
        _Pragma("unroll") for (int j2 = 0; j2 < 4; ++j2)                         \
            acc[i2][j2] = MFMA16(aL[i2], bL[j2], acc[i2][j2]);                   \
    __builtin_amdgcn_s_setprio(0);                                               \
    __builtin_amdgcn_s_barrier();                                                \
    _Pragma("unroll") for (int q2 = 0; q2 < 4; ++q2)                             \
        aH[q2] = *(const v8h*)(Ab_ + 2048 + q2 * 512);                           \
    if (DOST) stageB((TS), (SH));                                                \
    __builtin_amdgcn_s_barrier();                                                \
    asm volatile("s_waitcnt lgkmcnt(0)" ::: "memory");                           \
    __builtin_amdgcn_s_setprio(1);                                               \
    _Pragma("unroll") for (int i2 = 0; i2 < 4; ++i2)                             \
        _Pragma("unroll") for (int j2 = 0; j2 < 4; ++j2)                         \
            acc[4 + i2][j2] = MFMA16(aH[i2], bL[j2], acc[4 + i2][j2]);           \
    __builtin_amdgcn_s_setprio(0);                                               \
    if (DOVM) asm volatile("s_waitcnt " VM ::: "memory");                        \
    __builtin_amdgcn_s_barrier();                                                \
} while (0)

    // 32 K-steps; main loop p=0..27, peel 28..31 with tapered waits
    for (int tt = 0; tt < 14; tt += 2) {
        QKV_KSTEP(0, tt + 1, 1, true, "vmcnt(8)", true);
        QKV_KSTEP(1, tt + 2, 0, true, "vmcnt(8)", true);
        QKV_KSTEP(2, tt + 2, 1, true, "vmcnt(8)", true);
        QKV_KSTEP(3, tt + 3, 0, true, "vmcnt(8)", true);
    }
    QKV_KSTEP(0, 15, 1, true,  "vmcnt(8)", true);   // p=28: stages last slot 31
    QKV_KSTEP(1, 0, 0, false, "vmcnt(4)", true);    // p=29
    QKV_KSTEP(2, 0, 0, false, "vmcnt(0)", true);    // p=30
    QKV_KSTEP(3, 0, 0, false, "vmcnt(0)", false);   // p=31 (no wait)
#undef QKV_KSTEP

    const int sec = n0 >> 10;                      // block-uniform: 0=Q 1=K 2=V
    if (sec < 2) {
        _Float16* C = sec ? Ko : Qo;
        // Q pre-scaled by 1/sqrt(DK) * log2(e) so flash uses exp2 directly
        const float scale = sec ? 1.0f : 0.125f * 1.44269504f;
#pragma unroll
        for (int mf = 0; mf < 8; ++mf) {
            const int mbase = m0 + wm * 128 + mf * 16 + quad * 4;
#pragma unroll
            for (int nf = 0; nf < 4; ++nf) {
                const int nl = (n0 + wn * 64 + nf * 16 + l16) & 1023;
                const int h = nl >> 6, dk = nl & 63;
#pragma unroll
                for (int r = 0; r < 4; ++r) {
                    const int m = mbase + r, b = m >> 11, nr = m & (Nn - 1);
                    C[((size_t)(b * Hn + h) * Nn + nr) * DKn + dk] = (_Float16)(acc[mf][nf][r] * scale);
                }
            }
        }
    } else {
#pragma unroll
        for (int mf = 0; mf < 8; ++mf) {
            const int mbase = m0 + wm * 128 + mf * 16 + quad * 4;
            const int b = mbase >> 11, nr = mbase & (Nn - 1);
#pragma unroll
            for (int nf = 0; nf < 4; ++nf) {
                const int nl = (n0 + wn * 64 + nf * 16 + l16) & 1023;
                const int h = nl >> 6, dk = nl & 63;
                h4 o; o[0] = (_Float16)acc[mf][nf][0]; o[1] = (_Float16)acc[mf][nf][1];
                o[2] = (_Float16)acc[mf][nf][2]; o[3] = (_Float16)acc[mf][nf][3];
                *(h4*)&Vo[((size_t)(b * Hn + h) * DKn + dk) * Nn + nr] = o;
            }
        }
    }
}

// ---------- output GEMM: [8192,1024] @ [1024,1024]^T -> fp32 row-major ----------
// 256x128 tile (grid 256 = exactly 1 full round of 256 CUs), per-wave 64x64.
__global__ __launch_bounds__(512, 2) void gemmo(const _Float16* __restrict__ A,
                                                const _Float16* __restrict__ Wt,
                                                float* __restrict__ C)
{
    __shared__ __align__(16) _Float16 As[4 * 8192];
    __shared__ __align__(16) _Float16 Bs[4 * 4096];
    // XCD swizzle: 256 % 8 == 0 -> 32 tiles/XCD, contiguous (by,bx) range
    const int wgid = (blockIdx.x & 7) * 32 + (blockIdx.x >> 3);
    const int bx = wgid & 7, by = wgid >> 3;
    const int m0 = by * 256, n0 = bx * 128;
    const _Float16* Abase = A + (size_t)m0 * Dn;
    const _Float16* Bbase = Wt + (size_t)n0 * Dn;

    const int t = threadIdx.x, lane = t & 63, w = t >> 6;
    const int quad = lane >> 4, l16 = lane & 15;
    const int wm = w & 3, wn = w >> 2;
    const int rA = t >> 2;
    const int gc = ((t & 3) ^ ((t >> 3) & 3)) * 8;
    const _Float16* pA0 = Abase + (size_t)rA * Dn + gc;
    const _Float16* pA1 = pA0 + (size_t)128 * Dn;
    const _Float16* pB0 = Bbase + (size_t)rA * Dn + gc;
    auto stage3 = [&](int ts, int sh) {
        const int reg = (ts & 1) * 2 + sh, ko = ts * 64 + sh * 32;
        load_lds16(pA0 + ko, As + reg * 8192 + w * 512);
        load_lds16(pA1 + ko, As + reg * 8192 + 4096 + w * 512);
        load_lds16(pB0 + ko, Bs + reg * 4096 + w * 512);
    };
    const int swz  = (quad ^ ((l16 >> 1) & 3)) * 8;
    const int aoff = (wm * 64 + l16) * 32 + swz;
    const int boff = (wn * 64 + l16) * 32 + swz;

    v4f acc[4][4];
#pragma unroll
    for (int i = 0; i < 4; ++i)
#pragma unroll
        for (int j = 0; j < 4; ++j) acc[i][j] = v4f{0.f, 0.f, 0.f, 0.f};

    stage3(0, 0); stage3(0, 1); stage3(1, 0);    // prologue: slots 0,1,2
    asm volatile("s_waitcnt vmcnt(6)" ::: "memory");
    __builtin_amdgcn_s_barrier();

#define O_KSTEP(REG, TS, SH, DOST, VM, DOVM) do {                                \
    const _Float16* Ab_ = As + (REG) * 8192 + aoff;                              \
    const _Float16* Bb_ = Bs + (REG) * 4096 + boff;                              \
    v8h aL[4], bL[4];                                                            \
    _Pragma("unroll") for (int q2 = 0; q2 < 4; ++q2) {                           \
        aL[q2] = *(const v8h*)(Ab_ + q2 * 512);                                  \
        bL[q2] = *(const v8h*)(Bb_ + q2 * 512);                                  \
    }                                                                            \
    if (DOST) stage3((TS), (SH));                                                \
    __builtin_amdgcn_s_barrier();                                                \
    asm volatile("s_waitcnt lgkmcnt(0)" ::: "memory");                           \
    __builtin_amdgcn_s_setprio(1);                                               \
    _Pragma("unroll") for (int i2 = 0; i2 < 4; ++i2)                             \
        _Pragma("unroll") for (int j2 = 0; j2 < 4; ++j2)                         \
            acc[i2][j2] = MFMA16(aL[i2], bL[j2], acc[i2][j2]);                   \
    __builtin_amdgcn_s_setprio(0);                                               \
    if (DOVM) asm volatile("s_waitcnt " VM ::: "memory");                        \
    __builtin_amdgcn_s_barrier();                                                \
} while (0)

    for (int tt = 0; tt < 14; tt += 2) {
        O_KSTEP(0, tt + 1, 1, true, "vmcnt(6)", true);
        O_KSTEP(1, tt + 2, 0, true, "vmcnt(6)", true);
        O_KSTEP(2, tt + 2, 1, true, "vmcnt(6)", true);
        O_KSTEP(3, tt + 3, 0, true, "vmcnt(6)", true);
    }
    O_KSTEP(0, 15, 1, true,  "vmcnt(6)", true);   // p=28
    O_KSTEP(1, 0, 0, false, "vmcnt(3)", true);    // p=29
    O_KSTEP(2, 0, 0, false, "vmcnt(0)", true);    // p=30
    O_KSTEP(3, 0, 0, false, "vmcnt(0)", false);   // p=31
#undef O_KSTEP

#pragma unroll
    for (int mf = 0; mf < 4; ++mf) {
        const int mbase = m0 + wm * 64 + mf * 16 + quad * 4;
#pragma unroll
        for (int nf = 0; nf < 4; ++nf) {
            const int n = n0 + wn * 64 + nf * 16 + l16;
#pragma unroll
            for (int r = 0; r < 4; ++r)
                C[(size_t)(mbase + r) * Dn + n] = acc[mf][nf][r];
        }
    }
}

// ---------------- flash v5 (R6 version, single-buffer) ----------------
// R7's K/V double-buffer REGRESSED (-6us): 48KB LDS cut occupancy 5->3
// blocks/CU while K/V (512KB/head) is L2-resident across the 16 q-tile
// blocks per bh -> staging latency was already TLP-hidden (Common-mistake
// #7: don't pipeline data that cache-fits). Reverted. Blocks sharing bh are
// bid (mod 64) apart -> same XCD already (64 % 8 == 0): K/V L2 affinity ok.
__global__ __launch_bounds__(256) void flashv5(const _Float16* __restrict__ Q,
                                               const _Float16* __restrict__ K,
                                               const _Float16* __restrict__ Vt,
                                               _Float16* __restrict__ O)
{
    __shared__ __align__(16) _Float16 KS[64 * 64];     // [key][dk], chunk-swizzled
    __shared__ __align__(16) _Float16 VS[64 * 64];     // [dk][key], chunk-swizzled
    __shared__ __align__(16) _Float16 Ps[4][32 * 64];  // per-wave P, chunk-swizzled

    const int t = threadIdx.x;
    const int lane = t & 63, w = t >> 6;
    const int quad = lane >> 4, l16 = lane & 15;
    const int bh = blockIdx.x & 63;                    // fast-varying (L2 locality)
    const int qtile = 15 - (blockIdx.x >> 6);          // heaviest first
    const int b = bh >> 4, h = bh & 15;
    const int qb = qtile * 128 + w * 32;

    const _Float16* Qg = Q  + (size_t)bh * Nn * DKn;
    const _Float16* Kg = K  + (size_t)bh * Nn * DKn;
    const _Float16* Vg = Vt + (size_t)bh * DKn * Nn;

    auto stage = [&](int kt) {
        const int k0 = kt * 64;
#pragma unroll
        for (int jj = 0; jj < 2; ++jj) {
            const int ci = jj * 256 + w * 64 + lane;   // slot (r*8 + c)
            const int r = ci >> 3, c = ci & 7;
            const int gc = (c ^ (r & 7)) * 8;          // XOR chunk swizzle
            load_lds16(Kg + (size_t)(k0 + r) * DKn + gc, &KS[(jj * 256 + w * 64) * 8]);
            load_lds16(Vg + (size_t)r * Nn + k0 + gc,    &VS[(jj * 256 + w * 64) * 8]);
        }
    };
#define SWZ(arr, r, c) (*(const v8h*)&(arr)[(r) * 64 + (((c) ^ ((r) & 7)) * 8)])

    v8h qf[2][2];
#pragma unroll
    for (int qq = 0; qq < 2; ++qq)
#pragma unroll
        for (int ks = 0; ks < 2; ++ks)
            qf[qq][ks] = *(const v8h*)&Qg[(size_t)(qb + qq * 16 + l16) * DKn + ks * 32 + quad * 8];

    v8h ones;
#pragma unroll
    for (int i = 0; i < 8; ++i) ones[i] = (_Float16)1.0f;

    v4f o[2][4];
#pragma unroll
    for (int mq = 0; mq < 2; ++mq)
#pragma unroll
        for (int nt = 0; nt < 4; ++nt) o[mq][nt] = v4f{0.f, 0.f, 0.f, 0.f};
    v4f ol[2] = {v4f{0.f, 0.f, 0.f, 0.f}, v4f{0.f, 0.f, 0.f, 0.f}};

    const int NKT  = 2 * qtile + 2;                    // block-uniform
    const int diag = 2 * qtile + (w >> 1);             // wave's masked tile

    for (int kt = 0; kt < NKT; ++kt) {
        stage(kt);
        __syncthreads();                               // drains vmcnt (staging done)
        if (kt <= diag) {
            const int k0 = kt * 64;
            auto ptile = [&](bool domask) {
#pragma unroll
                for (int kk = 0; kk < 4; ++kk) {
                    v4f s0 = v4f{0.f, 0.f, 0.f, 0.f}, s1 = v4f{0.f, 0.f, 0.f, 0.f};
#pragma unroll
                    for (int ks = 0; ks < 2; ++ks) {
                        const v8h ak = SWZ(KS, kk * 16 + l16, ks * 4 + quad);
                        s0 = __builtin_amdgcn_mfma_f32_16x16x32_f16(ak, qf[0][ks], s0, 0, 0, 0);
                        s1 = __builtin_amdgcn_mfma_f32_16x16x32_f16(ak, qf[1][ks], s1, 0, 0, 0);
                    }
                    const int key0 = k0 + kk * 16 + quad * 4;
#pragma unroll
                    for (int qq = 0; qq < 2; ++qq) {
                        const v4f sv = qq ? s1 : s0;
                        const int q = qb + qq * 16 + l16;
                        float p[4];
#pragma unroll
                        for (int r = 0; r < 4; ++r) {
                            float x = sv[r];
                            if (domask) x = (key0 + r > q) ? -1e9f : x;
                            p[r] = FEXP2(x);           // Q pre-scaled by log2e/8
                        }
                        f2x2 pkr;
                        pkr.lo = __builtin_amdgcn_cvt_pkrtz(p[0], p[1]);
                        pkr.hi = __builtin_amdgcn_cvt_pkrtz(p[2], p[3]);
                        const h4 pk = __builtin_bit_cast(h4, pkr);
                        const int prow = qq * 16 + l16;
                        const int pch  = kk * 2 + (quad >> 1);
                        *(h4*)&Ps[w][prow * 64 + ((pch ^ (prow & 7)) * 8 + (quad & 1) * 4)] = pk;
                    }
                }
#pragma unroll
                for (int ks = 0; ks < 2; ++ks)
#pragma unroll
                    for (int mq = 0; mq < 2; ++mq) {
                        const int arow = mq * 16 + l16;
                        const int ach  = ks * 4 + quad;
                        const v8h a = *(const v8h*)&Ps[w][arow * 64 + ((ach ^ (arow & 7)) * 8)];
#pragma unroll
                        for (int nt = 0; nt < 4; ++nt) {
                            const v8h bvv = SWZ(VS, nt * 16 + l16, ks * 4 + quad);
                            o[mq][nt] = __builtin_amdgcn_mfma_f32_16x16x32_f16(a, bvv, o[mq][nt], 0, 0, 0);
                        }
                        ol[mq] = __builtin_amdgcn_mfma_f32_16x16x32_f16(a, ones, ol[mq], 0, 0, 0);
                    }
            };
            if (kt == diag) ptile(true); else ptile(false);
        }
        __syncthreads();                               // all reads done before next stage
    }
#undef SWZ

    _Float16* Op = O + (size_t)b * Nn * Dn + h * DKn;
#pragma unroll
    for (int mq = 0; mq < 2; ++mq)
#pragma unroll
        for (int r = 0; r < 4; ++r) {
            const float li = 1.0f / ol[mq][r];
            const int qrow = qb + mq * 16 + quad * 4 + r;
#pragma unroll
            for (int nt = 0; nt < 4; ++nt)
                Op[(size_t)qrow * Dn + nt * 16 + l16] = (_Float16)(o[mq][nt][r] * li);
        }
}

extern "C" void kernel_launch(void* const* d_in, const int* in_sizes, int n_in,
                              void* d_out, int out_size, void* d_ws, size_t ws_size,
                              hipStream_t stream)
{
    const float* X  = (const float*)d_in[0];
    // d_in[1] = additive causal mask; regenerated inline in flashv5.
    const float* Wq = (const float*)d_in[2];
    const float* Wk = (const float*)d_in[3];
    const float* Wv = (const float*)d_in[4];
    const float* Wo = (const float*)d_in[5];

    char* ws = (char*)d_ws;
    _Float16* Xh   = (_Float16*)ws;                      // 16 MB
    _Float16* Wqkv = (_Float16*)(ws + (16u << 20));      // 6 MB  [3072][1024]
    _Float16* Wto  = Wqkv + (3u << 20);                  // 2 MB
    _Float16* Qh   = Wto + (1u << 20);                   // 16 MB each
    _Float16* Kh   = Qh + (size_t)Mn * Dn;
    _Float16* Vth  = Kh + (size_t)Mn * Dn;
    _Float16* Ah   = Vth + (size_t)Mn * Dn;              // total 88 MB

    castAll<<<12288, 256, 0, stream>>>(X, Xh, Wq, Wk, Wv, Wo, Wqkv, Wto);
    gemmqkv<<<384, 512, 0, stream>>>(Xh, Wqkv, Qh, Kh, Vth);
    flashv5<<<1024, 256, 0, stream>>>(Qh, Kh, Vth, Ah);
    gemmo<<<256, 512, 0, stream>>>(Ah, Wto, (float*)d_out);
}